// Round 1
// baseline (1111.418 us; speedup 1.0000x reference)
//
#include <hip/hip_runtime.h>
#include <hip/hip_bf16.h>
#include <math.h>

// Problem constants
#define TT 1024      // tokens (B*S)
#define HD 1024      // hidden
#define NE 8         // experts
#define ID 2048      // intermediate
#define MAXSLOT 2560 // 2048 assignments + 8*64 padding, rounded
constexpr float JEPS = 0.01f;

__device__ __forceinline__ float silu_f(float v) {
    return v / (1.f + expf(-v));
}

// ---------------- Kernel 1: gating (one wave per token) ----------------
__global__ __launch_bounds__(256) void gate_kernel(
    const float* __restrict__ x, const float* __restrict__ gw,
    int* __restrict__ sel, float* __restrict__ wgt, int* __restrict__ counts)
{
    int wave = threadIdx.x >> 6;
    int lane = threadIdx.x & 63;
    int t = blockIdx.x * 4 + wave;

    const float4* x4 = (const float4*)(x + (size_t)t * HD);
    const float4* g4 = (const float4*)gw;

    float acc[8] = {0.f,0.f,0.f,0.f,0.f,0.f,0.f,0.f};
    #pragma unroll
    for (int c = 0; c < 4; ++c) {
        float4 xv = x4[lane + c * 64];
        #pragma unroll
        for (int e = 0; e < 8; ++e) {
            float4 gv = g4[e * 256 + lane + c * 64];
            acc[e] += xv.x*gv.x + xv.y*gv.y + xv.z*gv.z + xv.w*gv.w;
        }
    }
    #pragma unroll
    for (int e = 0; e < 8; ++e) {
        float v = acc[e];
        #pragma unroll
        for (int off = 32; off > 0; off >>= 1) v += __shfl_xor(v, off, 64);
        acc[e] = v;
    }

    if (lane == 0) {
        float s[8];
        #pragma unroll
        for (int e = 0; e < 8; ++e) s[e] = acc[e];

        // top-1 (first occurrence on ties, matching jax top_k)
        int i0 = 0; float t1 = s[0];
        #pragma unroll
        for (int e = 1; e < 8; ++e) { if (s[e] > t1) { t1 = s[e]; i0 = e; } }
        // top-2 excluding i0
        int i1 = -1; float t2 = -INFINITY;
        #pragma unroll
        for (int e = 0; e < 8; ++e) {
            if (e == i0) continue;
            if (s[e] > t2) { t2 = s[e]; i1 = e; }
        }

        // mult1 = softmax(where((t1-s)/max(|s|,t1) > 2eps, -inf, s))[i0]
        float sum1 = 0.f;
        #pragma unroll
        for (int e = 0; e < 8; ++e) {
            if (e == i0) { sum1 += 1.f; continue; }
            float f = fmaxf(fabsf(s[e]), t1);
            bool masked = (t1 - s[e]) > 2.f * JEPS * f;  // f>=0; equal semantics incl. 0/0
            if (!masked) sum1 += expf(s[e] - t1);
        }
        float w0 = 1.f / sum1;

        // mult2: scores with i0 -> -inf, mask vs t2
        float sum2 = 0.f;
        #pragma unroll
        for (int e = 0; e < 8; ++e) {
            if (e == i0) continue;
            if (e == i1) { sum2 += 1.f; continue; }
            float f = fmaxf(fabsf(s[e]), t2);
            bool masked = (t2 - s[e]) > 2.f * JEPS * f;
            if (!masked) sum2 += expf(s[e] - t2);
        }
        float w1v = 1.f / sum2;

        sel[t * 2 + 0] = i0; sel[t * 2 + 1] = i1;
        wgt[t * 2 + 0] = w0; wgt[t * 2 + 1] = w1v;
        atomicAdd(&counts[i0], 1);
        atomicAdd(&counts[i1], 1);
    }
}

// ---------------- Kernel 2: padded prefix offsets ----------------
__global__ void offsets_kernel(const int* __restrict__ counts,
                               int* __restrict__ offs, int* __restrict__ cursor)
{
    int o = 0;
    for (int e = 0; e < NE; ++e) {
        offs[e] = o;
        cursor[e] = o;
        o += (counts[e] + 63) & ~63;  // pad each expert region to 64
    }
}

// ---------------- Kernel 3: scatter tokens to expert slots ----------------
__global__ __launch_bounds__(256) void scatter_kernel(
    const int* __restrict__ sel, const float* __restrict__ wgt,
    int* __restrict__ cursor, int* __restrict__ slot_token,
    float* __restrict__ slot_weight)
{
    int t = blockIdx.x * 256 + threadIdx.x;
    #pragma unroll
    for (int j = 0; j < 2; ++j) {
        int e = sel[t * 2 + j];
        int pos = atomicAdd(&cursor[e], 1);
        slot_token[pos] = t;
        slot_weight[pos] = wgt[t * 2 + j];
    }
}

// ---------------- Kernel 4: FFN1 — act = silu(x@w1^T) * (x@w3^T) ----------------
// grid (tt=16, it=32, e=8), block 256. Tile: 64 slots x 64 intermediates, K-tile 32.
__global__ __launch_bounds__(256) void ffn1_kernel(
    const float* __restrict__ x, const float* __restrict__ w1,
    const float* __restrict__ w3, const int* __restrict__ counts,
    const int* __restrict__ offs, const int* __restrict__ slot_token,
    float* __restrict__ act)
{
    int e = blockIdx.z, it = blockIdx.y, tt = blockIdx.x;
    int cnt = counts[e];
    if (tt * 64 >= cnt) return;
    int base = offs[e];

    __shared__ float Xs[32][64];   // [k][slot-row]
    __shared__ float W1s[32][64];  // [k][i-col]
    __shared__ float W3s[32][64];

    int tid = threadIdx.x;
    int row = tid >> 2;           // 0..63
    int kq  = (tid & 3) * 8;      // 0,8,16,24

    int srow = tt * 64 + row;
    int tok = (srow < cnt) ? slot_token[base + srow] : 0;
    const float* xrow  = x  + (size_t)tok * HD;
    const float* w1row = w1 + ((size_t)e * ID + it * 64 + row) * HD;
    const float* w3row = w3 + ((size_t)e * ID + it * 64 + row) * HD;

    int ty = tid >> 4, tx = tid & 15;
    float a1[4][4] = {};
    float a3[4][4] = {};

    for (int kt = 0; kt < HD; kt += 32) {
        __syncthreads();
        float4 xv0 = *(const float4*)(xrow  + kt + kq);
        float4 xv1 = *(const float4*)(xrow  + kt + kq + 4);
        float4 w10 = *(const float4*)(w1row + kt + kq);
        float4 w11 = *(const float4*)(w1row + kt + kq + 4);
        float4 w30 = *(const float4*)(w3row + kt + kq);
        float4 w31 = *(const float4*)(w3row + kt + kq + 4);
        Xs[kq+0][row]=xv0.x; Xs[kq+1][row]=xv0.y; Xs[kq+2][row]=xv0.z; Xs[kq+3][row]=xv0.w;
        Xs[kq+4][row]=xv1.x; Xs[kq+5][row]=xv1.y; Xs[kq+6][row]=xv1.z; Xs[kq+7][row]=xv1.w;
        W1s[kq+0][row]=w10.x; W1s[kq+1][row]=w10.y; W1s[kq+2][row]=w10.z; W1s[kq+3][row]=w10.w;
        W1s[kq+4][row]=w11.x; W1s[kq+5][row]=w11.y; W1s[kq+6][row]=w11.z; W1s[kq+7][row]=w11.w;
        W3s[kq+0][row]=w30.x; W3s[kq+1][row]=w30.y; W3s[kq+2][row]=w30.z; W3s[kq+3][row]=w30.w;
        W3s[kq+4][row]=w31.x; W3s[kq+5][row]=w31.y; W3s[kq+6][row]=w31.z; W3s[kq+7][row]=w31.w;
        __syncthreads();

        #pragma unroll 8
        for (int kk = 0; kk < 32; ++kk) {
            float4 xv = *(const float4*)&Xs[kk][ty * 4];
            float4 b1 = *(const float4*)&W1s[kk][tx * 4];
            float4 b3 = *(const float4*)&W3s[kk][tx * 4];
            float xa[4] = {xv.x, xv.y, xv.z, xv.w};
            float v1[4] = {b1.x, b1.y, b1.z, b1.w};
            float v3[4] = {b3.x, b3.y, b3.z, b3.w};
            #pragma unroll
            for (int m = 0; m < 4; ++m) {
                #pragma unroll
                for (int n = 0; n < 4; ++n) {
                    a1[m][n] += xa[m] * v1[n];
                    a3[m][n] += xa[m] * v3[n];
                }
            }
        }
    }

    // epilogue: act[(base + tt*64 + r) * ID + it*64 + c] = silu(a1)*a3
    size_t arowbase = ((size_t)(base + tt * 64)) * ID + (size_t)(it * 64);
    #pragma unroll
    for (int m = 0; m < 4; ++m) {
        int r = ty * 4 + m;
        float4 o;
        o.x = silu_f(a1[m][0]) * a3[m][0];
        o.y = silu_f(a1[m][1]) * a3[m][1];
        o.z = silu_f(a1[m][2]) * a3[m][2];
        o.w = silu_f(a1[m][3]) * a3[m][3];
        *(float4*)&act[arowbase + (size_t)r * ID + tx * 4] = o;
    }
}

// ---------------- Kernel 5: FFN2 — out[tok] += w * (act @ w2^T) ----------------
// grid (tt=16, ht=16, e=8), block 256. Tile: 64 slots x 64 hidden, K-tile 32 over I=2048.
__global__ __launch_bounds__(256) void ffn2_kernel(
    const float* __restrict__ act, const float* __restrict__ w2,
    const int* __restrict__ counts, const int* __restrict__ offs,
    const int* __restrict__ slot_token, const float* __restrict__ slot_weight,
    float* __restrict__ out)
{
    int e = blockIdx.z, ht = blockIdx.y, tt = blockIdx.x;
    int cnt = counts[e];
    if (tt * 64 >= cnt) return;
    int base = offs[e];

    __shared__ float As[32][64];  // [k][slot-row]
    __shared__ float Bs[32][64];  // [k][h-col]

    int tid = threadIdx.x;
    int row = tid >> 2;
    int kq  = (tid & 3) * 8;

    const float* arow  = act + ((size_t)(base + tt * 64 + row)) * ID;
    const float* w2row = w2  + ((size_t)e * HD + ht * 64 + row) * ID;

    int ty = tid >> 4, tx = tid & 15;
    float acc[4][4] = {};

    for (int kt = 0; kt < ID; kt += 32) {
        __syncthreads();
        float4 a0 = *(const float4*)(arow  + kt + kq);
        float4 a1 = *(const float4*)(arow  + kt + kq + 4);
        float4 b0 = *(const float4*)(w2row + kt + kq);
        float4 b1 = *(const float4*)(w2row + kt + kq + 4);
        As[kq+0][row]=a0.x; As[kq+1][row]=a0.y; As[kq+2][row]=a0.z; As[kq+3][row]=a0.w;
        As[kq+4][row]=a1.x; As[kq+5][row]=a1.y; As[kq+6][row]=a1.z; As[kq+7][row]=a1.w;
        Bs[kq+0][row]=b0.x; Bs[kq+1][row]=b0.y; Bs[kq+2][row]=b0.z; Bs[kq+3][row]=b0.w;
        Bs[kq+4][row]=b1.x; Bs[kq+5][row]=b1.y; Bs[kq+6][row]=b1.z; Bs[kq+7][row]=b1.w;
        __syncthreads();

        #pragma unroll 8
        for (int kk = 0; kk < 32; ++kk) {
            float4 av = *(const float4*)&As[kk][ty * 4];
            float4 bv = *(const float4*)&Bs[kk][tx * 4];
            float aa[4] = {av.x, av.y, av.z, av.w};
            float bb[4] = {bv.x, bv.y, bv.z, bv.w};
            #pragma unroll
            for (int m = 0; m < 4; ++m) {
                #pragma unroll
                for (int n = 0; n < 4; ++n) acc[m][n] += aa[m] * bb[n];
            }
        }
    }

    #pragma unroll
    for (int m = 0; m < 4; ++m) {
        int r = tt * 64 + ty * 4 + m;
        if (r < cnt) {
            int tok  = slot_token[base + r];
            float wv = slot_weight[base + r];
            float* orow = out + (size_t)tok * HD + ht * 64 + tx * 4;
            #pragma unroll
            for (int n = 0; n < 4; ++n) atomicAdd(&orow[n], wv * acc[m][n]);
        }
    }
}

// ---------------- host launch ----------------
extern "C" void kernel_launch(void* const* d_in, const int* in_sizes, int n_in,
                              void* d_out, int out_size, void* d_ws, size_t ws_size,
                              hipStream_t stream)
{
    const float* x  = (const float*)d_in[0];  // (1,1024,1024)
    const float* gw = (const float*)d_in[1];  // (8,1024)
    const float* w1 = (const float*)d_in[2];  // (8,2048,1024)
    const float* w2 = (const float*)d_in[3];  // (8,1024,2048)
    const float* w3 = (const float*)d_in[4];  // (8,2048,1024)
    float* out = (float*)d_out;

    char* w = (char*)d_ws;
    int*   counts      = (int*)(w + 0);        // 8 ints
    int*   offs        = (int*)(w + 64);       // 8 ints
    int*   cursor      = (int*)(w + 128);      // 8 ints
    int*   sel         = (int*)(w + 256);      // 2048 ints
    float* wgt         = (float*)(w + 256 + 8192);
    int*   slot_token  = (int*)(w + 256 + 16384);            // MAXSLOT ints
    float* slot_weight = (float*)(w + 256 + 16384 + 4*MAXSLOT);
    float* act         = (float*)(w + 65536);  // MAXSLOT * ID floats = 20 MB

    hipMemsetAsync(counts, 0, 64, stream);
    hipMemsetAsync(d_out, 0, (size_t)TT * HD * sizeof(float), stream);

    gate_kernel<<<TT / 4, 256, 0, stream>>>(x, gw, sel, wgt, counts);
    offsets_kernel<<<1, 1, 0, stream>>>(counts, offs, cursor);
    scatter_kernel<<<TT / 256, 256, 0, stream>>>(sel, wgt, cursor, slot_token, slot_weight);
    ffn1_kernel<<<dim3(16, 32, 8), 256, 0, stream>>>(x, w1, w3, counts, offs, slot_token, act);
    ffn2_kernel<<<dim3(16, 16, 8), 256, 0, stream>>>(act, w2, counts, offs, slot_token, slot_weight, out);
}

// Round 2
// 265.757 us; speedup vs baseline: 4.1821x; 4.1821x over previous
//
#include <hip/hip_runtime.h>
#include <hip/hip_bf16.h>
#include <math.h>

// Problem constants
#define TT 1024      // tokens (B*S)
#define HD 1024      // hidden
#define NE 8         // experts
#define ID 2048      // intermediate
#define MAXSLOT 3072 // 2048 assignments + 8*127 padding, rounded up
constexpr float JEPS = 0.01f;

typedef __attribute__((ext_vector_type(8))) short bf16x8;
typedef __attribute__((ext_vector_type(4))) float f32x4;

__device__ __forceinline__ float silu_f(float v) {
    return v / (1.f + expf(-v));
}

// fp32 -> bf16 (round-to-nearest-even), raw ushort
__device__ __forceinline__ unsigned short f2bf(float f) {
    unsigned int u = __float_as_uint(f);
    u += 0x7FFF + ((u >> 16) & 1);
    return (unsigned short)(u >> 16);
}

// convert float4 -> 4 bf16 and store 8B to LDS (p must be 8B aligned)
__device__ __forceinline__ void st_bf4(unsigned short* p, float4 v) {
    union { unsigned short u[4]; uint2 q; } pk;
    pk.u[0] = f2bf(v.x); pk.u[1] = f2bf(v.y);
    pk.u[2] = f2bf(v.z); pk.u[3] = f2bf(v.w);
    *(uint2*)p = pk.q;
}

// ---------------- Kernel 1: gating (one wave per token) ----------------
__global__ __launch_bounds__(256) void gate_kernel(
    const float* __restrict__ x, const float* __restrict__ gw,
    int* __restrict__ sel, float* __restrict__ wgt, int* __restrict__ counts)
{
    int wave = threadIdx.x >> 6;
    int lane = threadIdx.x & 63;
    int t = blockIdx.x * 4 + wave;

    const float4* x4 = (const float4*)(x + (size_t)t * HD);
    const float4* g4 = (const float4*)gw;

    float acc[8] = {0.f,0.f,0.f,0.f,0.f,0.f,0.f,0.f};
    #pragma unroll
    for (int c = 0; c < 4; ++c) {
        float4 xv = x4[lane + c * 64];
        #pragma unroll
        for (int e = 0; e < 8; ++e) {
            float4 gv = g4[e * 256 + lane + c * 64];
            acc[e] += xv.x*gv.x + xv.y*gv.y + xv.z*gv.z + xv.w*gv.w;
        }
    }
    #pragma unroll
    for (int e = 0; e < 8; ++e) {
        float v = acc[e];
        #pragma unroll
        for (int off = 32; off > 0; off >>= 1) v += __shfl_xor(v, off, 64);
        acc[e] = v;
    }

    if (lane == 0) {
        float s[8];
        #pragma unroll
        for (int e = 0; e < 8; ++e) s[e] = acc[e];

        int i0 = 0; float t1 = s[0];
        #pragma unroll
        for (int e = 1; e < 8; ++e) { if (s[e] > t1) { t1 = s[e]; i0 = e; } }
        int i1 = -1; float t2 = -INFINITY;
        #pragma unroll
        for (int e = 0; e < 8; ++e) {
            if (e == i0) continue;
            if (s[e] > t2) { t2 = s[e]; i1 = e; }
        }

        float sum1 = 0.f;
        #pragma unroll
        for (int e = 0; e < 8; ++e) {
            if (e == i0) { sum1 += 1.f; continue; }
            float f = fmaxf(fabsf(s[e]), t1);
            bool masked = (t1 - s[e]) > 2.f * JEPS * f;
            if (!masked) sum1 += expf(s[e] - t1);
        }
        float w0 = 1.f / sum1;

        float sum2 = 0.f;
        #pragma unroll
        for (int e = 0; e < 8; ++e) {
            if (e == i0) continue;
            if (e == i1) { sum2 += 1.f; continue; }
            float f = fmaxf(fabsf(s[e]), t2);
            bool masked = (t2 - s[e]) > 2.f * JEPS * f;
            if (!masked) sum2 += expf(s[e] - t2);
        }
        float w1v = 1.f / sum2;

        sel[t * 2 + 0] = i0; sel[t * 2 + 1] = i1;
        wgt[t * 2 + 0] = w0; wgt[t * 2 + 1] = w1v;
        atomicAdd(&counts[i0], 1);
        atomicAdd(&counts[i1], 1);
    }
}

// ---------------- Kernel 2: padded prefix offsets (pad to 128) ----------------
__global__ void offsets_kernel(const int* __restrict__ counts,
                               int* __restrict__ offs, int* __restrict__ cursor)
{
    int o = 0;
    for (int e = 0; e < NE; ++e) {
        offs[e] = o;
        cursor[e] = o;
        o += (counts[e] + 127) & ~127;
    }
}

// ---------------- Kernel 3: scatter tokens to expert slots ----------------
__global__ __launch_bounds__(256) void scatter_kernel(
    const int* __restrict__ sel, const float* __restrict__ wgt,
    int* __restrict__ cursor, int* __restrict__ slot_token,
    float* __restrict__ slot_weight)
{
    int t = blockIdx.x * 256 + threadIdx.x;
    #pragma unroll
    for (int j = 0; j < 2; ++j) {
        int e = sel[t * 2 + j];
        int pos = atomicAdd(&cursor[e], 1);
        slot_token[pos] = t;
        slot_weight[pos] = wgt[t * 2 + j];
    }
}

// ---------------- Kernel 4: FFN1 (MFMA bf16) ----------------
// Tile: 128 slots x 64 intermediate, BK=32. 4 waves as 2x2, each 64x32 (4x2 frags).
// grid (tt=8, it=32, e=8), block 256.
__global__ __launch_bounds__(256) void ffn1_kernel(
    const float* __restrict__ x, const float* __restrict__ w1,
    const float* __restrict__ w3, const int* __restrict__ counts,
    const int* __restrict__ offs, const int* __restrict__ slot_token,
    unsigned short* __restrict__ act)
{
    int e = blockIdx.z, it = blockIdx.y, tt = blockIdx.x;
    int cnt = counts[e];
    if (tt * 128 >= cnt) return;
    int base = offs[e];

    __shared__ unsigned short Xs[128][40];   // [slot-row][k], pad 40 => 2-way max
    __shared__ unsigned short W1s[64][40];   // [i-col-row][k]
    __shared__ unsigned short W3s[64][40];

    int t = threadIdx.x;
    // X staging: 128 rows x 8 float4-segs; 2 threads/row, 4 segs each
    int xr = t >> 1, xs0 = (t & 1) * 4;
    int srow = tt * 128 + xr;
    int tok = (srow < cnt) ? slot_token[base + srow] : slot_token[base];
    const float* xptr = x + (size_t)tok * HD;
    // W staging: 64 rows x 8 segs; 4 threads/row, segs ws0 and ws0+4
    int wrow = t >> 2, ws0 = t & 3;
    const float* w1ptr = w1 + ((size_t)e * ID + (size_t)it * 64 + wrow) * HD;
    const float* w3ptr = w3 + ((size_t)e * ID + (size_t)it * 64 + wrow) * HD;

    int wid = t >> 6, lane = t & 63;
    int wr = wid >> 1, wc = wid & 1;        // wave owns rows wr*64..+64, cols wc*32..+32
    int fr = lane & 15, fg = lane >> 4;

    f32x4 a1[4][2], a3[4][2];
    #pragma unroll
    for (int m = 0; m < 4; ++m)
        #pragma unroll
        for (int n = 0; n < 2; ++n) {
            a1[m][n] = (f32x4){0.f, 0.f, 0.f, 0.f};
            a3[m][n] = (f32x4){0.f, 0.f, 0.f, 0.f};
        }

    for (int kt = 0; kt < HD; kt += 32) {
        float4 xv[4], w1v[2], w3v[2];
        #pragma unroll
        for (int j = 0; j < 4; ++j)
            xv[j] = *(const float4*)(xptr + kt + (xs0 + j) * 4);
        w1v[0] = *(const float4*)(w1ptr + kt + ws0 * 4);
        w1v[1] = *(const float4*)(w1ptr + kt + (ws0 + 4) * 4);
        w3v[0] = *(const float4*)(w3ptr + kt + ws0 * 4);
        w3v[1] = *(const float4*)(w3ptr + kt + (ws0 + 4) * 4);
        __syncthreads();
        #pragma unroll
        for (int j = 0; j < 4; ++j) st_bf4(&Xs[xr][(xs0 + j) * 4], xv[j]);
        st_bf4(&W1s[wrow][ws0 * 4], w1v[0]);
        st_bf4(&W1s[wrow][(ws0 + 4) * 4], w1v[1]);
        st_bf4(&W3s[wrow][ws0 * 4], w3v[0]);
        st_bf4(&W3s[wrow][(ws0 + 4) * 4], w3v[1]);
        __syncthreads();

        bf16x8 af[4], b1f[2], b3f[2];
        #pragma unroll
        for (int m = 0; m < 4; ++m)
            af[m] = *(const bf16x8*)&Xs[wr * 64 + m * 16 + fr][fg * 8];
        #pragma unroll
        for (int n = 0; n < 2; ++n) {
            b1f[n] = *(const bf16x8*)&W1s[wc * 32 + n * 16 + fr][fg * 8];
            b3f[n] = *(const bf16x8*)&W3s[wc * 32 + n * 16 + fr][fg * 8];
        }
        #pragma unroll
        for (int m = 0; m < 4; ++m)
            #pragma unroll
            for (int n = 0; n < 2; ++n) {
                a1[m][n] = __builtin_amdgcn_mfma_f32_16x16x32_bf16(af[m], b1f[n], a1[m][n], 0, 0, 0);
                a3[m][n] = __builtin_amdgcn_mfma_f32_16x16x32_bf16(af[m], b3f[n], a3[m][n], 0, 0, 0);
            }
    }

    // epilogue: act (bf16) = silu(a1) * a3.  C/D: col=lane&15, row=(lane>>4)*4+reg
    size_t rowbase = (size_t)(base + tt * 128);
    #pragma unroll
    for (int m = 0; m < 4; ++m)
        #pragma unroll
        for (int n = 0; n < 2; ++n)
            #pragma unroll
            for (int r = 0; r < 4; ++r) {
                int lrow = wr * 64 + m * 16 + fg * 4 + r;
                int col  = it * 64 + wc * 32 + n * 16 + fr;
                float v = silu_f(a1[m][n][r]) * a3[m][n][r];
                act[(rowbase + lrow) * ID + col] = f2bf(v);
            }
}

// ---------------- Kernel 5: FFN2 (MFMA bf16) ----------------
// Tile: 128 slots x 64 hidden, BK=32 over I=2048. grid (tt=8, ht=16, e=8).
__global__ __launch_bounds__(256) void ffn2_kernel(
    const unsigned short* __restrict__ act, const float* __restrict__ w2,
    const int* __restrict__ counts, const int* __restrict__ offs,
    const int* __restrict__ slot_token, const float* __restrict__ slot_weight,
    float* __restrict__ out)
{
    int e = blockIdx.z, ht = blockIdx.y, tt = blockIdx.x;
    int cnt = counts[e];
    if (tt * 128 >= cnt) return;
    int base = offs[e];

    __shared__ unsigned short As[128][40];
    __shared__ unsigned short Bs[64][40];

    int t = threadIdx.x;
    // act staging: 128 rows x 4 uint4-segs (16B); 2 threads/row, 2 segs each
    int ar = t >> 1, as0 = (t & 1) * 2;
    const unsigned short* aptr = act + (size_t)(base + tt * 128 + ar) * ID;
    // w2 staging: 64 rows x 8 float4-segs; 4 threads/row
    int wrow = t >> 2, ws0 = t & 3;
    const float* w2ptr = w2 + ((size_t)e * HD + (size_t)ht * 64 + wrow) * ID;

    int wid = t >> 6, lane = t & 63;
    int wr = wid >> 1, wc = wid & 1;
    int fr = lane & 15, fg = lane >> 4;

    f32x4 acc[4][2];
    #pragma unroll
    for (int m = 0; m < 4; ++m)
        #pragma unroll
        for (int n = 0; n < 2; ++n) acc[m][n] = (f32x4){0.f, 0.f, 0.f, 0.f};

    for (int kt = 0; kt < ID; kt += 32) {
        uint4 av0 = *(const uint4*)(aptr + kt + as0 * 8);
        uint4 av1 = *(const uint4*)(aptr + kt + (as0 + 1) * 8);
        float4 w2v0 = *(const float4*)(w2ptr + kt + ws0 * 4);
        float4 w2v1 = *(const float4*)(w2ptr + kt + (ws0 + 4) * 4);
        __syncthreads();
        *(uint4*)&As[ar][as0 * 8] = av0;
        *(uint4*)&As[ar][(as0 + 1) * 8] = av1;
        st_bf4(&Bs[wrow][ws0 * 4], w2v0);
        st_bf4(&Bs[wrow][(ws0 + 4) * 4], w2v1);
        __syncthreads();

        bf16x8 af[4], bf[2];
        #pragma unroll
        for (int m = 0; m < 4; ++m)
            af[m] = *(const bf16x8*)&As[wr * 64 + m * 16 + fr][fg * 8];
        #pragma unroll
        for (int n = 0; n < 2; ++n)
            bf[n] = *(const bf16x8*)&Bs[wc * 32 + n * 16 + fr][fg * 8];
        #pragma unroll
        for (int m = 0; m < 4; ++m)
            #pragma unroll
            for (int n = 0; n < 2; ++n)
                acc[m][n] = __builtin_amdgcn_mfma_f32_16x16x32_bf16(af[m], bf[n], acc[m][n], 0, 0, 0);
    }

    #pragma unroll
    for (int m = 0; m < 4; ++m)
        #pragma unroll
        for (int r = 0; r < 4; ++r) {
            int grow = tt * 128 + wr * 64 + m * 16 + fg * 4 + r;
            if (grow < cnt) {
                int tok  = slot_token[base + grow];
                float wv = slot_weight[base + grow];
                float* orow = out + (size_t)tok * HD + ht * 64 + wc * 32;
                #pragma unroll
                for (int n = 0; n < 2; ++n)
                    atomicAdd(&orow[n * 16 + fr], wv * acc[m][n][r]);
            }
        }
}

// ---------------- host launch ----------------
extern "C" void kernel_launch(void* const* d_in, const int* in_sizes, int n_in,
                              void* d_out, int out_size, void* d_ws, size_t ws_size,
                              hipStream_t stream)
{
    const float* x  = (const float*)d_in[0];  // (1,1024,1024)
    const float* gw = (const float*)d_in[1];  // (8,1024)
    const float* w1 = (const float*)d_in[2];  // (8,2048,1024)
    const float* w2 = (const float*)d_in[3];  // (8,1024,2048)
    const float* w3 = (const float*)d_in[4];  // (8,2048,1024)
    float* out = (float*)d_out;

    char* w = (char*)d_ws;
    int*   counts      = (int*)(w + 0);
    int*   offs        = (int*)(w + 64);
    int*   cursor      = (int*)(w + 128);
    int*   sel         = (int*)(w + 256);
    float* wgt         = (float*)(w + 256 + 8192);
    int*   slot_token  = (int*)(w + 16640);                 // MAXSLOT ints
    float* slot_weight = (float*)(w + 16640 + 4 * MAXSLOT);
    unsigned short* act = (unsigned short*)(w + 65536);     // MAXSLOT * ID bf16 = 12.6 MB

    hipMemsetAsync(counts, 0, 64, stream);
    hipMemsetAsync(d_out, 0, (size_t)TT * HD * sizeof(float), stream);

    gate_kernel<<<TT / 4, 256, 0, stream>>>(x, gw, sel, wgt, counts);
    offsets_kernel<<<1, 1, 0, stream>>>(counts, offs, cursor);
    scatter_kernel<<<TT / 256, 256, 0, stream>>>(sel, wgt, cursor, slot_token, slot_weight);
    ffn1_kernel<<<dim3(8, 32, 8), 256, 0, stream>>>(x, w1, w3, counts, offs, slot_token, act);
    ffn2_kernel<<<dim3(8, 16, 8), 256, 0, stream>>>(act, w2, counts, offs, slot_token, slot_weight, out);
}